// Round 4
// baseline (147.727 us; speedup 1.0000x reference)
//
#include <hip/hip_runtime.h>
#include <hip/hip_bf16.h>
#include <stdint.h>

typedef unsigned int u32;

#define BATCH 64
#define ROOT 128
#define NLEAF 7
#define LHEAD 4
#define HDIM 128
#define NNODES 1024
#define OUTROWS 1025
#define NREL1 65          // NUM_REL + 1

typedef __attribute__((ext_vector_type(8))) short bf16x8;   // 4 VGPRs (guide §3)
typedef __attribute__((ext_vector_type(4))) float f32x4;

// Per-relation precomputed (rewritten every launch — idempotent):
//   g_U = M^T r_even, g_V = M^T r_odd (fp32)
//   g_Mfrag = M as bf16 in MFMA A-fragment order:
//     dword index per rel: ((r*4 + t)*64 + lane)*4 + dw
//     holds M[i=r*16+(lane&15)][j=t*32+(lane>>4)*8+dw*2 (+1 in hi half)]
__device__ float g_U[NREL1 * HDIM];
__device__ float g_V[NREL1 * HDIM];
__device__ u32   g_Mfrag[NREL1 * 8192];

static __device__ __forceinline__ u32 rne_bf16(float f) {
    u32 u = __builtin_bit_cast(u32, f);
    return (u + 0x7fffu + ((u >> 16) & 1u)) >> 16;
}
static __device__ __forceinline__ u32 pack_bf16(float a, float b) {
    return rne_bf16(a) | (rne_bf16(b) << 16);
}

// ---------------------------------------------------------------------------
// prep_kernel: grid (65, 8), block 256.
//  part 0..3 : pack one quarter of M[rel] into g_Mfrag (A-fragment order)
//  part 4..7 : U/V for one 32-wide j-strip, i split 8 ways + LDS tree reduce
// ---------------------------------------------------------------------------
__global__ void prep_kernel(const float* __restrict__ rel_mat,
                            const float* __restrict__ rel_emb) {
    int rel = blockIdx.x;
    int part = blockIdx.y;
    const float* M = rel_mat + (size_t)rel * HDIM * HDIM;
    __shared__ float red_u[8][32], red_v[8][32];

    if (part < 4) {
        u32* dst = &g_Mfrag[(size_t)rel * 8192];
        #pragma unroll
        for (int q = 0; q < 8; ++q) {
            int o = part * 2048 + q * 256 + threadIdx.x;   // 0..8191
            int r  = o >> 10;
            int t  = (o >> 8) & 3;
            int ln = (o >> 2) & 63;
            int dw = o & 3;
            int i = r * 16 + (ln & 15);
            int j = t * 32 + ((ln >> 4) << 3) + dw * 2;
            dst[o] = pack_bf16(M[i * HDIM + j], M[i * HDIM + j + 1]);
        }
    } else {
        int p = part - 4;
        int jj = threadIdx.x & 31, s = threadIdx.x >> 5;   // 32 j × 8 i-slices
        int j = p * 32 + jj;
        const float* r = rel_emb + (size_t)rel * 2 * HDIM;
        float u = 0.f, v = 0.f;
        #pragma unroll
        for (int ii = 0; ii < 16; ++ii) {
            int i = s * 16 + ii;
            float m = M[i * HDIM + j];
            u += r[2 * i] * m;
            v += r[2 * i + 1] * m;
        }
        red_u[s][jj] = u; red_v[s][jj] = v;
        __syncthreads();
        if (s == 0) {
            float su = 0.f, sv = 0.f;
            #pragma unroll
            for (int q = 0; q < 8; ++q) { su += red_u[q][jj]; sv += red_v[q][jj]; }
            g_U[rel * HDIM + j] = su;
            g_V[rel * HDIM + j] = sv;
        }
    }
}

// ---------------------------------------------------------------------------
// triple_kernel: one block per (rn, b). 256 threads, ~6 KB LDS.
//   Mh via MFMA 16x16x32_bf16: wave w computes rows 32w..32w+31.
//   A-frags coalesced from g_Mfrag; B-frags built from global atom rows.
//   root row + graph token folded in.
// ---------------------------------------------------------------------------
__global__ __launch_bounds__(256) void triple_kernel(
    const int* __restrict__ tok,
    const int* __restrict__ leaf_rel,
    const float* __restrict__ atom,
    const float* __restrict__ gtok,
    float* __restrict__ out)
{
    int rn = blockIdx.x;
    int b  = blockIdx.y;
    int tid = threadIdx.x;
    int wave = tid >> 6, lane = tid & 63;

    __shared__ float te_s[NLEAF * HDIM];                 // [t][j]
    __shared__ __align__(16) float Mh_s[HDIM * LHEAD];   // [i][l]
    __shared__ float a_s[NLEAF], b_s[LHEAD];
    __shared__ float alpha_s[NLEAF * LHEAD];
    __shared__ int s_tok[LHEAD + NLEAF];

    int rel = leaf_rel[b * ROOT + rn];

    // ---- A-fragment loads: wave w owns row-tiles 2w, 2w+1 (coalesced x4) ----
    const uint4* Mf = ((const uint4*)g_Mfrag) + (size_t)rel * 2048;
    uint4 afr[8];                                        // [r2*4 + t]
    #pragma unroll
    for (int r2 = 0; r2 < 2; ++r2)
        #pragma unroll
        for (int t = 0; t < 4; ++t)
            afr[r2 * 4 + t] = Mf[((2 * wave + r2) * 4 + t) * 64 + lane];

    // ---- tokens ----
    if (tid < LHEAD) {
        int hp = rn + tid; if (hp > ROOT - 1) hp = ROOT - 1;   // torch clip
        s_tok[tid] = tok[b * NNODES + hp];
    } else if (tid < LHEAD + NLEAF) {
        s_tok[tid] = tok[b * NNODES + ROOT + rn * NLEAF + (tid - LHEAD)];
    }
    __syncthreads();

    // ---- te gather ([t][j] fp32) ----
    #pragma unroll
    for (int e = tid; e < NLEAF * HDIM; e += 256) {
        int j = e & 127;
        te_s[e] = atom[(size_t)s_tok[LHEAD + (e >> 7)] * HDIM + j];
    }

    // ---- B-fragments from global he rows (fp32 -> bf16), cols n>=4 replicate ----
    int bl = lane & 3;                       // head index feeding col n (n&3)
    int kb = (lane >> 4) << 3;               // k base within 32-wide k-tile
    const float* hrow = atom + (size_t)s_tok[bl] * HDIM;
    uint4 bfr[4];
    #pragma unroll
    for (int t = 0; t < 4; ++t) {
        float4 f0 = *(const float4*)(hrow + t * 32 + kb);
        float4 f1 = *(const float4*)(hrow + t * 32 + kb + 4);
        bfr[t].x = pack_bf16(f0.x, f0.y);
        bfr[t].y = pack_bf16(f0.z, f0.w);
        bfr[t].z = pack_bf16(f1.x, f1.y);
        bfr[t].w = pack_bf16(f1.z, f1.w);
    }
    __syncthreads();

    // ---- 11 length-128 dots (fp32), round-robin across 4 waves ----
    const float* u = &g_U[rel * HDIM];
    const float* v = &g_V[rel * HDIM];
    for (int d = wave; d < NLEAF + LHEAD; d += 4) {
        float p;
        if (d < NLEAF) {
            p = u[lane]      * te_s[d * HDIM + lane]
              + u[lane + 64] * te_s[d * HDIM + lane + 64];
        } else {
            const float* he = atom + (size_t)s_tok[d - NLEAF] * HDIM;
            p = v[lane] * he[lane] + v[lane + 64] * he[lane + 64];
        }
        #pragma unroll
        for (int m = 32; m > 0; m >>= 1) p += __shfl_xor(p, m, 64);
        if (lane == 0) {
            if (d < NLEAF) a_s[d] = p; else b_s[d - NLEAF] = p;
        }
    }
    __syncthreads();

    // ---- softmax over 4 heads per tail (leaky_relu slope 0.01) ----
    if (tid < NLEAF) {
        float sc[LHEAD];
        float mx = -1e30f;
        #pragma unroll
        for (int l = 0; l < LHEAD; ++l) {
            float x = a_s[tid] + b_s[l];
            x = (x >= 0.f) ? x : 0.01f * x;
            sc[l] = x; mx = fmaxf(mx, x);
        }
        float sum = 0.f;
        #pragma unroll
        for (int l = 0; l < LHEAD; ++l) { sc[l] = __expf(sc[l] - mx); sum += sc[l]; }
        float inv = 1.f / sum;
        #pragma unroll
        for (int l = 0; l < LHEAD; ++l) alpha_s[tid * LHEAD + l] = sc[l] * inv;
    }

    // ---- MFMA: Mh[i][l] = sum_j M[i][j] he[l][j]; D col=lane&15, row=(lane>>4)*4+reg ----
    f32x4 acc0 = {0.f, 0.f, 0.f, 0.f}, acc1 = {0.f, 0.f, 0.f, 0.f};
    #pragma unroll
    for (int t = 0; t < 4; ++t) {
        bf16x8 bt = __builtin_bit_cast(bf16x8, bfr[t]);
        acc0 = __builtin_amdgcn_mfma_f32_16x16x32_bf16(
                   __builtin_bit_cast(bf16x8, afr[t]),     bt, acc0, 0, 0, 0);
        acc1 = __builtin_amdgcn_mfma_f32_16x16x32_bf16(
                   __builtin_bit_cast(bf16x8, afr[4 + t]), bt, acc1, 0, 0, 0);
    }
    {
        int n = lane & 15;
        if (n < LHEAD) {
            int mrow = (lane >> 4) * 4;
            #pragma unroll
            for (int reg = 0; reg < 4; ++reg) {
                Mh_s[((2 * wave)     * 16 + mrow + reg) * LHEAD + n] = acc0[reg];
                Mh_s[((2 * wave + 1) * 16 + mrow + reg) * LHEAD + n] = acc1[reg];
            }
        }
    }

    // ---- root row + graph token (independent global writes) ----
    size_t bbase = (size_t)b * OUTROWS * HDIM;
    if (tid < HDIM) {
        out[bbase + (size_t)(1 + rn) * HDIM + tid] = atom[(size_t)s_tok[0] * HDIM + tid];
        if (rn == 0) out[bbase + tid] = gtok[tid];
    }
    __syncthreads();

    // ---- leaf outputs: te + alpha·Mh ----
    size_t obase = bbase + (size_t)(1 + ROOT + rn * NLEAF) * HDIM;
    #pragma unroll
    for (int e = tid; e < NLEAF * HDIM; e += 256) {
        int t = e >> 7, j = e & 127;
        const float4 mh = *(const float4*)&Mh_s[j * LHEAD];
        const float* al = &alpha_s[t * LHEAD];
        out[obase + e] = te_s[e] + al[0]*mh.x + al[1]*mh.y + al[2]*mh.z + al[3]*mh.w;
    }
}

// ---------------------------------------------------------------------------
extern "C" void kernel_launch(void* const* d_in, const int* in_sizes, int n_in,
                              void* d_out, int out_size, void* d_ws, size_t ws_size,
                              hipStream_t stream) {
    (void)in_sizes; (void)n_in; (void)out_size; (void)d_ws; (void)ws_size;
    const int* tok       = (const int*)d_in[0];     // [B,1024,1] int32
    const int* leaf_rel  = (const int*)d_in[1];     // [B,128]    int32
    // d_in[2] = head_lengths: unused by the reference body
    const float* atom    = (const float*)d_in[3];   // [30000,128] fp32
    const float* rel_mat = (const float*)d_in[4];   // [65,128*128] fp32
    const float* rel_emb = (const float*)d_in[5];   // [65,256] fp32
    const float* gtok    = (const float*)d_in[6];   // [1,128] fp32
    float* out = (float*)d_out;                     // [64,1025,128] fp32

    dim3 pgrid(NREL1, 8);
    prep_kernel<<<pgrid, 256, 0, stream>>>(rel_mat, rel_emb);

    dim3 grid(ROOT, BATCH);
    triple_kernel<<<grid, 256, 0, stream>>>(tok, leaf_rel, atom, gtok, out);
}

// Round 5
// 117.418 us; speedup vs baseline: 1.2581x; 1.2581x over previous
//
#include <hip/hip_runtime.h>
#include <hip/hip_bf16.h>
#include <stdint.h>

typedef unsigned int u32;

#define BATCH 64
#define ROOT 128
#define NLEAF 7
#define LHEAD 4
#define HDIM 128
#define NNODES 1024
#define OUTROWS 1025
#define NREL1 65          // NUM_REL + 1

typedef __attribute__((ext_vector_type(8))) short bf16x8;
typedef __attribute__((ext_vector_type(4))) float f32x4;

// Per-relation precomputed (rewritten every launch — idempotent):
//   g_U = M^T r_even, g_V = M^T r_odd (fp32)
//   g_Mfrag = M as bf16 in MFMA A-fragment order:
//     uint4 index per rel: (rt*4 + kt)*64 + lane
//     holds M[i=rt*16+(lane&15)][k=kt*32+(lane>>4)*8 + 0..7]
__device__ float g_U[NREL1 * HDIM];
__device__ float g_V[NREL1 * HDIM];
__device__ u32   g_Mfrag[NREL1 * 8192];

static __device__ __forceinline__ u32 rne_bf16(float f) {
    u32 u = __builtin_bit_cast(u32, f);
    return (u + 0x7fffu + ((u >> 16) & 1u)) >> 16;
}
static __device__ __forceinline__ u32 pack_bf16(float a, float b) {
    return rne_bf16(a) | (rne_bf16(b) << 16);
}

// ---------------------------------------------------------------------------
// prep_kernel: grid (65, 8), block 256.
//  part 0..3 : pack one quarter of M[rel] into g_Mfrag (A-fragment order)
//  part 4..7 : U/V for one 32-wide j-strip, i split 8 ways + LDS tree reduce
// ---------------------------------------------------------------------------
__global__ void prep_kernel(const float* __restrict__ rel_mat,
                            const float* __restrict__ rel_emb) {
    int rel = blockIdx.x;
    int part = blockIdx.y;
    const float* M = rel_mat + (size_t)rel * HDIM * HDIM;
    __shared__ float red_u[8][32], red_v[8][32];

    if (part < 4) {
        u32* dst = &g_Mfrag[(size_t)rel * 8192];
        #pragma unroll
        for (int q = 0; q < 8; ++q) {
            int o = part * 2048 + q * 256 + threadIdx.x;   // 0..8191 dwords
            int r  = o >> 10;
            int t  = (o >> 8) & 3;
            int ln = (o >> 2) & 63;
            int dw = o & 3;
            int i = r * 16 + (ln & 15);
            int j = t * 32 + ((ln >> 4) << 3) + dw * 2;
            dst[o] = pack_bf16(M[i * HDIM + j], M[i * HDIM + j + 1]);
        }
    } else {
        int p = part - 4;
        int jj = threadIdx.x & 31, s = threadIdx.x >> 5;   // 32 j × 8 i-slices
        int j = p * 32 + jj;
        const float* r = rel_emb + (size_t)rel * 2 * HDIM;
        float u = 0.f, v = 0.f;
        #pragma unroll
        for (int ii = 0; ii < 16; ++ii) {
            int i = s * 16 + ii;
            float m = M[i * HDIM + j];
            u += r[2 * i] * m;
            v += r[2 * i + 1] * m;
        }
        red_u[s][jj] = u; red_v[s][jj] = v;
        __syncthreads();
        if (s == 0) {
            float su = 0.f, sv = 0.f;
            #pragma unroll
            for (int q = 0; q < 8; ++q) { su += red_u[q][jj]; sv += red_v[q][jj]; }
            g_U[rel * HDIM + j] = su;
            g_V[rel * HDIM + j] = sv;
        }
    }
}

// ---------------------------------------------------------------------------
// triple_kernel: grid (32, 64), 256 threads = 4 waves; ONE WAVE OWNS ONE
// TRIPLE end-to-end. Zero __syncthreads — all LDS traffic is wave-local
// (compiler-inserted lgkmcnt orders within-wave RAW).
// ---------------------------------------------------------------------------
__global__ __launch_bounds__(256) void triple_kernel(
    const int* __restrict__ tok,
    const int* __restrict__ leaf_rel,
    const float* __restrict__ atom,
    const float* __restrict__ gtok,
    float* __restrict__ out)
{
    int g = blockIdx.x;                 // root group (4 roots per block)
    int b = blockIdx.y;
    int tid = threadIdx.x;
    int wave = tid >> 6, lane = tid & 63;
    int rn = g * 4 + wave;              // this wave's root/triple

    // per-wave LDS regions (no cross-wave sharing)
    __shared__ __align__(16) float MhT[4][LHEAD][HDIM];      // [wave][l][i]  8 KB
    __shared__ float asb[4][16];                             // [wave][0..6]=a, [8..11]=b
    __shared__ __align__(16) float alpha_s[4][NLEAF][LHEAD]; // [wave][t][l]
    __shared__ int stok[4][12];

    int rel = leaf_rel[b * ROOT + rn];  // wave-uniform

    // ---- tokens: lanes 0..10 load this wave's 4 heads + 7 tails ----
    if (lane < LHEAD + NLEAF) {
        int idx;
        if (lane < LHEAD) {
            int hp = rn + lane; if (hp > ROOT - 1) hp = ROOT - 1;   // torch clip
            idx = tok[b * NNODES + hp];
        } else {
            idx = tok[b * NNODES + ROOT + rn * NLEAF + (lane - LHEAD)];
        }
        stok[wave][lane] = idx;
    }

    // ---- u/v weight slices for the dots (L2-hot) ----
    const float* U = &g_U[rel * HDIM];
    const float* V = &g_V[rel * HDIM];
    float u_lo = U[lane], u_hi = U[lane + 64];
    float v_lo = V[lane], v_hi = V[lane + 64];

    // ---- 11 length-128 dots: d<7 -> a[t]=U·te[t], else b[l]=V·he[l] ----
    // All 22 global loads independent (full unroll) -> latency overlapped by ILP.
    #pragma unroll
    for (int d = 0; d < NLEAF + LHEAD; ++d) {
        int trow = (d < NLEAF) ? (LHEAD + d) : (d - NLEAF);
        const float* row = atom + (size_t)stok[wave][trow] * HDIM;
        float w0 = (d < NLEAF) ? u_lo : v_lo;
        float w1 = (d < NLEAF) ? u_hi : v_hi;
        float p = w0 * row[lane] + w1 * row[lane + 64];
        #pragma unroll
        for (int m = 32; m > 0; m >>= 1) p += __shfl_xor(p, m, 64);
        if (lane == 0) asb[wave][(d < NLEAF) ? d : (8 + d - NLEAF)] = p;
    }

    // ---- softmax over 4 heads per tail (leaky_relu slope 0.01), lanes 0..6 ----
    if (lane < NLEAF) {
        float av = asb[wave][lane];
        float sc[LHEAD];
        float mx = -1e30f;
        #pragma unroll
        for (int l = 0; l < LHEAD; ++l) {
            float x = av + asb[wave][8 + l];
            x = (x >= 0.f) ? x : 0.01f * x;
            sc[l] = x; mx = fmaxf(mx, x);
        }
        float sum = 0.f;
        #pragma unroll
        for (int l = 0; l < LHEAD; ++l) { sc[l] = __expf(sc[l] - mx); sum += sc[l]; }
        float inv = 1.f / sum;
        #pragma unroll
        for (int l = 0; l < LHEAD; ++l) alpha_s[wave][lane][l] = sc[l] * inv;
    }

    // ---- B-fragments from global he rows (fp32 -> bf16); col n -> head n&3 ----
    int nn = lane & 15;                      // MFMA col
    int kb = (lane >> 4) << 3;               // k-chunk base within 32-wide k-tile
    const float* hrow = atom + (size_t)stok[wave][nn & 3] * HDIM;
    uint4 bfr[4];
    #pragma unroll
    for (int t = 0; t < 4; ++t) {
        float4 f0 = *(const float4*)(hrow + t * 32 + kb);
        float4 f1 = *(const float4*)(hrow + t * 32 + kb + 4);
        bfr[t].x = pack_bf16(f0.x, f0.y);
        bfr[t].y = pack_bf16(f0.z, f0.w);
        bfr[t].z = pack_bf16(f1.x, f1.y);
        bfr[t].w = pack_bf16(f1.z, f1.w);
    }

    // ---- MFMA: full 128-row Mh for this wave's triple; rt-sequential accs ----
    // D layout: col=lane&15, row=(lane>>4)*4+reg (+rt*16). Store transposed so
    // the 4 regs land contiguous: MhT[l][row] as one b128 write.
    const uint4* Mf = ((const uint4*)g_Mfrag) + (size_t)rel * 2048;
    #pragma unroll
    for (int rt = 0; rt < 8; ++rt) {
        f32x4 acc = {0.f, 0.f, 0.f, 0.f};
        #pragma unroll
        for (int kt = 0; kt < 4; ++kt) {
            uint4 afr = Mf[(rt * 4 + kt) * 64 + lane];
            acc = __builtin_amdgcn_mfma_f32_16x16x32_bf16(
                      __builtin_bit_cast(bf16x8, afr),
                      __builtin_bit_cast(bf16x8, bfr[kt]), acc, 0, 0, 0);
        }
        if (nn < LHEAD) {
            int row0 = rt * 16 + ((lane >> 4) << 2);
            *(float4*)&MhT[wave][nn][row0] =
                make_float4(acc[0], acc[1], acc[2], acc[3]);
        }
    }

    // ---- root row + graph token ----
    size_t bbase = (size_t)b * OUTROWS * HDIM;
    {
        const float* rrow = atom + (size_t)stok[wave][0] * HDIM;
        out[bbase + (size_t)(1 + rn) * HDIM + lane]      = rrow[lane];
        out[bbase + (size_t)(1 + rn) * HDIM + lane + 64] = rrow[lane + 64];
        if (g == 0 && wave == 0) {
            out[bbase + lane]      = gtok[lane];
            out[bbase + lane + 64] = gtok[lane + 64];
        }
    }

    // ---- leaf outputs: out[t][j] = te[t][j] + sum_l alpha[t][l]*MhT[l][j] ----
    size_t obase = bbase + (size_t)(1 + ROOT + rn * NLEAF) * HDIM;
    #pragma unroll
    for (int e = 0; e < 14; ++e) {                 // 7*128/64
        int idx = e * 64 + lane;
        int t = idx >> 7, j = idx & 127;
        float tev = atom[(size_t)stok[wave][LHEAD + t] * HDIM + j];  // L2-warm re-read
        float4 al = *(const float4*)&alpha_s[wave][t][0];
        float r = tev + al.x * MhT[wave][0][j] + al.y * MhT[wave][1][j]
                      + al.z * MhT[wave][2][j] + al.w * MhT[wave][3][j];
        out[obase + idx] = r;
    }
}

// ---------------------------------------------------------------------------
extern "C" void kernel_launch(void* const* d_in, const int* in_sizes, int n_in,
                              void* d_out, int out_size, void* d_ws, size_t ws_size,
                              hipStream_t stream) {
    (void)in_sizes; (void)n_in; (void)out_size; (void)d_ws; (void)ws_size;
    const int* tok       = (const int*)d_in[0];     // [B,1024,1] int32
    const int* leaf_rel  = (const int*)d_in[1];     // [B,128]    int32
    // d_in[2] = head_lengths: unused by the reference body
    const float* atom    = (const float*)d_in[3];   // [30000,128] fp32
    const float* rel_mat = (const float*)d_in[4];   // [65,128*128] fp32
    const float* rel_emb = (const float*)d_in[5];   // [65,256] fp32
    const float* gtok    = (const float*)d_in[6];   // [1,128] fp32
    float* out = (float*)d_out;                     // [64,1025,128] fp32

    dim3 pgrid(NREL1, 8);
    prep_kernel<<<pgrid, 256, 0, stream>>>(rel_mat, rel_emb);

    dim3 grid(ROOT / 4, BATCH);
    triple_kernel<<<grid, 256, 0, stream>>>(tok, leaf_rel, atom, gtok, out);
}

// Round 6
// 109.547 us; speedup vs baseline: 1.3485x; 1.0718x over previous
//
#include <hip/hip_runtime.h>
#include <hip/hip_bf16.h>
#include <stdint.h>

typedef unsigned int u32;

#define BATCH 64
#define ROOT 128
#define NLEAF 7
#define LHEAD 4
#define HDIM 128
#define NNODES 1024
#define OUTROWS 1025
#define NREL1 65          // NUM_REL + 1
#define PSTR 132          // padded LDS row stride (dwords): 16B-aligned, de-conflicted

typedef __attribute__((ext_vector_type(8))) short bf16x8;
typedef __attribute__((ext_vector_type(4))) float f32x4;

// Per-relation precomputed (rewritten every launch — idempotent):
//   g_U = M^T r_even, g_V = M^T r_odd (fp32)
//   g_Mfrag = M as bf16 in MFMA A-fragment order:
//     uint4 index per rel: (rt*4 + kt)*64 + lane
//     holds M[i=rt*16+(lane&15)][k=kt*32+(lane>>4)*8 + 0..7]
__device__ float g_U[NREL1 * HDIM];
__device__ float g_V[NREL1 * HDIM];
__device__ u32   g_Mfrag[NREL1 * 8192];

static __device__ __forceinline__ u32 rne_bf16(float f) {
    u32 u = __builtin_bit_cast(u32, f);
    return (u + 0x7fffu + ((u >> 16) & 1u)) >> 16;
}
static __device__ __forceinline__ u32 pack_bf16(float a, float b) {
    return rne_bf16(a) | (rne_bf16(b) << 16);
}

// ---------------------------------------------------------------------------
// prep_kernel: grid (65, 8), block 256.
//  part 0..3 : pack one quarter of M[rel] into g_Mfrag (A-fragment order)
//  part 4..7 : U/V for one 32-wide j-strip, i split 8 ways + LDS tree reduce
// ---------------------------------------------------------------------------
__global__ void prep_kernel(const float* __restrict__ rel_mat,
                            const float* __restrict__ rel_emb) {
    int rel = blockIdx.x;
    int part = blockIdx.y;
    const float* M = rel_mat + (size_t)rel * HDIM * HDIM;
    __shared__ float red_u[8][32], red_v[8][32];

    if (part < 4) {
        u32* dst = &g_Mfrag[(size_t)rel * 8192];
        #pragma unroll
        for (int q = 0; q < 8; ++q) {
            int o = part * 2048 + q * 256 + threadIdx.x;   // 0..8191 dwords
            int r  = o >> 10;
            int t  = (o >> 8) & 3;
            int ln = (o >> 2) & 63;
            int dw = o & 3;
            int i = r * 16 + (ln & 15);
            int j = t * 32 + ((ln >> 4) << 3) + dw * 2;
            dst[o] = pack_bf16(M[i * HDIM + j], M[i * HDIM + j + 1]);
        }
    } else {
        int p = part - 4;
        int jj = threadIdx.x & 31, s = threadIdx.x >> 5;   // 32 j × 8 i-slices
        int j = p * 32 + jj;
        const float* r = rel_emb + (size_t)rel * 2 * HDIM;
        float u = 0.f, v = 0.f;
        #pragma unroll
        for (int ii = 0; ii < 16; ++ii) {
            int i = s * 16 + ii;
            float m = M[i * HDIM + j];
            u += r[2 * i] * m;
            v += r[2 * i + 1] * m;
        }
        red_u[s][jj] = u; red_v[s][jj] = v;
        __syncthreads();
        if (s == 0) {
            float su = 0.f, sv = 0.f;
            #pragma unroll
            for (int q = 0; q < 8; ++q) { su += red_u[q][jj]; sv += red_v[q][jj]; }
            g_U[rel * HDIM + j] = su;
            g_V[rel * HDIM + j] = sv;
        }
    }
}

// ---------------------------------------------------------------------------
// triple_kernel: grid (32, 64), 4 waves/block, ONE WAVE = ONE TRIPLE, zero
// __syncthreads. Each atom row loaded from global exactly once into regs:
//   te_lo/hi[7], he_lo/hi[4]  (dot layout == epilogue layout; he[0] == root row)
// Tokens broadcast lane->all via __shfl const-lane (v_readlane, no LDS).
// LDS only for: he B-frag relayout + MhT transpose (padded stride 132).
// ---------------------------------------------------------------------------
__global__ __launch_bounds__(256) void triple_kernel(
    const int* __restrict__ tok,
    const int* __restrict__ leaf_rel,
    const float* __restrict__ atom,
    const float* __restrict__ gtok,
    float* __restrict__ out)
{
    int g = blockIdx.x;                 // 4 roots per block
    int b = blockIdx.y;
    int tid = threadIdx.x;
    int wave = tid >> 6, lane = tid & 63;
    int rn = g * 4 + wave;

    __shared__ __align__(16) float he_s[4][LHEAD][PSTR];   // [wave][l][j]
    __shared__ __align__(16) float MhT[4][LHEAD][PSTR];    // [wave][l][i]

    int rel = leaf_rel[b * ROOT + rn];  // wave-uniform

    // ---- tokens: lanes 0..10 load, broadcast to SGPRs via const-lane shfl ----
    int tokidx = 0;
    if (lane < LHEAD + NLEAF) {
        int pos;
        if (lane < LHEAD) { int hp = rn + lane; if (hp > ROOT - 1) hp = ROOT - 1; pos = hp; }
        else              pos = ROOT + rn * NLEAF + (lane - LHEAD);
        tokidx = tok[b * NNODES + pos];
    }
    int htok[LHEAD], ttok[NLEAF];
    #pragma unroll
    for (int l = 0; l < LHEAD; ++l) htok[l] = __shfl(tokidx, l, 64);
    #pragma unroll
    for (int t = 0; t < NLEAF; ++t) ttok[t] = __shfl(tokidx, LHEAD + t, 64);

    // ---- each atom row ONCE into registers (11 x 2 independent loads) ----
    float he_lo[LHEAD], he_hi[LHEAD], te_lo[NLEAF], te_hi[NLEAF];
    #pragma unroll
    for (int l = 0; l < LHEAD; ++l) {
        const float* r = atom + (size_t)htok[l] * HDIM;
        he_lo[l] = r[lane]; he_hi[l] = r[lane + 64];
    }
    #pragma unroll
    for (int t = 0; t < NLEAF; ++t) {
        const float* r = atom + (size_t)ttok[t] * HDIM;
        te_lo[t] = r[lane]; te_hi[t] = r[lane + 64];
    }

    const float* U = &g_U[rel * HDIM];
    const float* V = &g_V[rel * HDIM];
    float u_lo = U[lane], u_hi = U[lane + 64];
    float v_lo = V[lane], v_hi = V[lane + 64];

    // ---- he -> LDS (for B-frag cross-lane relayout); conflict-free writes ----
    #pragma unroll
    for (int l = 0; l < LHEAD; ++l) {
        he_s[wave][l][lane]      = he_lo[l];
        he_s[wave][l][lane + 64] = he_hi[l];
    }

    // ---- 11 dots; xor-butterfly leaves the result in ALL lanes (no LDS) ----
    float a_r[NLEAF], b_r[LHEAD];
    #pragma unroll
    for (int t = 0; t < NLEAF; ++t) {
        float p = u_lo * te_lo[t] + u_hi * te_hi[t];
        #pragma unroll
        for (int m = 32; m > 0; m >>= 1) p += __shfl_xor(p, m, 64);
        a_r[t] = p;
    }
    #pragma unroll
    for (int l = 0; l < LHEAD; ++l) {
        float p = v_lo * he_lo[l] + v_hi * he_hi[l];
        #pragma unroll
        for (int m = 32; m > 0; m >>= 1) p += __shfl_xor(p, m, 64);
        b_r[l] = p;
    }

    // ---- B-fragments from he_s (b128 reads, padded stride) ----
    int nn = lane & 15;                  // MFMA col; head = nn&3 (cols 4..15 junk, never read)
    int kb = (lane >> 4) << 3;           // k-chunk base in 32-wide k-tile
    uint4 bfr[4];
    #pragma unroll
    for (int t = 0; t < 4; ++t) {
        const float* h = &he_s[wave][nn & 3][t * 32 + kb];
        float4 f0 = *(const float4*)h;
        float4 f1 = *(const float4*)(h + 4);
        bfr[t].x = pack_bf16(f0.x, f0.y);
        bfr[t].y = pack_bf16(f0.z, f0.w);
        bfr[t].z = pack_bf16(f1.x, f1.y);
        bfr[t].w = pack_bf16(f1.z, f1.w);
    }

    // ---- MFMA: Mh = M·he^T, 8 row-tiles, rt-sequential acc (4 VGPRs live) ----
    const uint4* Mf = ((const uint4*)g_Mfrag) + (size_t)rel * 2048;
    #pragma unroll
    for (int rt = 0; rt < 8; ++rt) {
        f32x4 acc = {0.f, 0.f, 0.f, 0.f};
        #pragma unroll
        for (int kt = 0; kt < 4; ++kt) {
            uint4 afr = Mf[(rt * 4 + kt) * 64 + lane];
            acc = __builtin_amdgcn_mfma_f32_16x16x32_bf16(
                      __builtin_bit_cast(bf16x8, afr),
                      __builtin_bit_cast(bf16x8, bfr[kt]), acc, 0, 0, 0);
        }
        if (nn < LHEAD) {                       // D: col=lane&15, row=(lane>>4)*4+reg
            int row0 = rt * 16 + ((lane >> 4) << 2);
            *(float4*)&MhT[wave][nn][row0] = make_float4(acc[0], acc[1], acc[2], acc[3]);
        }
    }

    // ---- root row (= he[0] regs) + graph token ----
    size_t bbase = (size_t)b * OUTROWS * HDIM;
    out[bbase + (size_t)(1 + rn) * HDIM + lane]      = he_lo[0];
    out[bbase + (size_t)(1 + rn) * HDIM + lane + 64] = he_hi[0];
    if (g == 0 && wave == 0) {
        out[bbase + lane]      = gtok[lane];
        out[bbase + lane + 64] = gtok[lane + 64];
    }

    // ---- epilogue: per tail, alpha in regs (uniform), te from regs ----
    size_t obase = bbase + (size_t)(1 + ROOT + rn * NLEAF) * HDIM;
    #pragma unroll
    for (int t = 0; t < NLEAF; ++t) {
        float sc[LHEAD]; float mx = -1e30f;
        #pragma unroll
        for (int l = 0; l < LHEAD; ++l) {
            float x = a_r[t] + b_r[l];
            x = (x >= 0.f) ? x : 0.01f * x;          // leaky_relu 0.01
            sc[l] = x; mx = fmaxf(mx, x);
        }
        float sum = 0.f;
        #pragma unroll
        for (int l = 0; l < LHEAD; ++l) { sc[l] = __expf(sc[l] - mx); sum += sc[l]; }
        float inv = 1.f / sum;
        float r0 = te_lo[t], r1 = te_hi[t];
        #pragma unroll
        for (int l = 0; l < LHEAD; ++l) {
            float al = sc[l] * inv;
            r0 += al * MhT[wave][l][lane];
            r1 += al * MhT[wave][l][lane + 64];
        }
        out[obase + t * HDIM + lane]      = r0;
        out[obase + t * HDIM + lane + 64] = r1;
    }
}

// ---------------------------------------------------------------------------
extern "C" void kernel_launch(void* const* d_in, const int* in_sizes, int n_in,
                              void* d_out, int out_size, void* d_ws, size_t ws_size,
                              hipStream_t stream) {
    (void)in_sizes; (void)n_in; (void)out_size; (void)d_ws; (void)ws_size;
    const int* tok       = (const int*)d_in[0];     // [B,1024,1] int32
    const int* leaf_rel  = (const int*)d_in[1];     // [B,128]    int32
    // d_in[2] = head_lengths: unused by the reference body
    const float* atom    = (const float*)d_in[3];   // [30000,128] fp32
    const float* rel_mat = (const float*)d_in[4];   // [65,128*128] fp32
    const float* rel_emb = (const float*)d_in[5];   // [65,256] fp32
    const float* gtok    = (const float*)d_in[6];   // [1,128] fp32
    float* out = (float*)d_out;                     // [64,1025,128] fp32

    dim3 pgrid(NREL1, 8);
    prep_kernel<<<pgrid, 256, 0, stream>>>(rel_mat, rel_emb);

    dim3 grid(ROOT / 4, BATCH);
    triple_kernel<<<grid, 256, 0, stream>>>(tok, leaf_rel, atom, gtok, out);
}